// Round 9
// baseline (29.383 us; speedup 1.0000x reference)
//
#include <hip/hip_runtime.h>

#define NSAMP 65536
#define DTF 1e-5f

// packed complex: f2.x = re, f2.y = im ; ops lower to v_pk_fma_f32
typedef float f2 __attribute__((ext_vector_type(2)));

__device__ __forceinline__ f2 ib(f2 b) { return (f2){-b.y, b.x}; }

// acc += a*b with bn = ib(b): two packed FMAs (a = scalar side)
__device__ __forceinline__ f2 cmac_p(f2 acc, f2 a, f2 b, f2 bn) {
    acc = a.y * bn + acc;
    acc = a.x * b + acc;
    return acc;
}

// Re(a * conj(b))
__device__ __forceinline__ float rec(f2 a, f2 b) { return a.x * b.x + a.y * b.y; }

// ---------------------------------------------------------------------------
// Pair-cooperative representation: lanes (2s, 2s+1) share one sample. Lane
// r = lane&1 stores the full 4x4 in its OWN basis (r=1: rows/cols (0,1)<->(2,3)
// swapped). Products compose inside each basis; partner exchange uses the
// fixed involution chunk c <-> c^5 (chunks = float4 = 2 f2). All register
// indices static; basis conversion at memory boundaries = address XOR only.
// ---------------------------------------------------------------------------

// merge own product-half Zh (rows 0,1 own basis) with partner's into full X
__device__ __forceinline__ void pair_merge(const f2* Zh, f2* X) {
#pragma unroll
    for (int j = 0; j < 8; ++j) X[j] = Zh[j];
#pragma unroll
    for (int u = 0; u < 4; ++u)
#pragma unroll
        for (int e = 0; e < 2; ++e) {
            f2 src = Zh[2 * (u ^ 1) + e];
            f2 d;
            d.x = __shfl_xor(src.x, 1, 64);
            d.y = __shfl_xor(src.y, 1, 64);
            X[8 + 2 * u + e] = d;
        }
}

// X <- X * Y (pair-cooperative; X,Y full 16 in own basis)
__device__ __forceinline__ void scan_mul(f2* X, const f2* Y) {
    f2 YN[16];
#pragma unroll
    for (int j = 0; j < 16; ++j) YN[j] = ib(Y[j]);
    f2 Zh[8];
#pragma unroll
    for (int i = 0; i < 2; ++i)
#pragma unroll
        for (int b = 0; b < 4; ++b) {
            f2 acc = (f2){0.f, 0.f};
#pragma unroll
            for (int k = 0; k < 4; ++k)
                acc = cmac_p(acc, X[4 * i + k], Y[4 * k + b], YN[4 * k + b]);
            Zh[4 * i + b] = acc;
        }
    pair_merge(Zh, X);
}

// gather full matrix from lane (lane - delta) — same r, same basis
__device__ __forceinline__ void gather_up(const f2* X, f2* Y, int delta) {
#pragma unroll
    for (int j = 0; j < 16; ++j) {
        Y[j].x = __shfl_up(X[j].x, (unsigned)delta, 64);
        Y[j].y = __shfl_up(X[j].y, (unsigned)delta, 64);
    }
}

// 5-round inclusive scan over the 32 sample-pairs of a wave
__device__ __forceinline__ void wave_scan_pair(f2* X, int s) {
#pragma unroll
    for (int off = 1; off < 32; off <<= 1) {
        f2 Y[16];
        gather_up(X, Y, 2 * off);
        if (s >= off) scan_mul(X, Y); // both pair lanes share s -> shfl safe
    }
}

// progressive combine over 8 waves; WT holds wave totals in CANONICAL chunks
__device__ __forceinline__ void block_combine_pair(f2* X, float4 (*WT)[8],
                                                   int w, int s, int r5) {
    if (w < 7 && s == 31) {
#pragma unroll
        for (int q = 0; q < 4; ++q)
            WT[w][q ^ r5] = make_float4(X[2 * q].x, X[2 * q].y,
                                        X[2 * q + 1].x, X[2 * q + 1].y);
    }
    __syncthreads();
    for (int k = w - 1; k >= 0; --k) {
        f2 Y[16];
#pragma unroll
        for (int c = 0; c < 8; ++c) {
            float4 v = WT[k][c ^ r5];
            Y[2 * c]     = (f2){v.x, v.y};
            Y[2 * c + 1] = (f2){v.z, v.w};
        }
        scan_mul(X, Y);
    }
}

// U = exp(-i*dt*H), order-6 Taylor (||dt H|| <= ~0.4), built in own basis
__device__ __forceinline__ void expmU_pair(float uxi, float uyi, float v1,
                                           float v2, float J, int r, f2* X) {
    const float twopi = 6.2831855f;
    float d0 = twopi * (0.5f * (v1 + v2) + 0.25f * J);
    float d1 = twopi * (0.5f * (v1 - v2) - 0.25f * J);
    float d2 = twopi * (0.5f * (v2 - v1) - 0.25f * J);
    float d3 = twopi * (-0.5f * (v1 + v2) + 0.25f * J);
    float g  = twopi * 0.5f * J;
    float cr = 0.5f * uxi;
    float ci = -0.5f * uyi;

    float e0 = r ? d2 : d0, e1 = r ? d3 : d1;
    float e2 = r ? d0 : d2, e3 = r ? d1 : d3;
    f2 c  = (f2){cr, ci}, cc = (f2){cr, -ci};
    f2 zz = (f2){0.f, 0.f}, gg = (f2){g, 0.f};

    // own-basis H: r=0 canonical; r=1 = half-swap conjugated (verified per-entry)
    f2 H[16];
    H[0]  = (f2){e0, 0.f}; H[1]  = c;             H[2]  = r ? cc : c;  H[3]  = r ? gg : zz;
    H[4]  = cc;            H[5]  = (f2){e1, 0.f}; H[6]  = r ? zz : gg; H[7]  = r ? cc : c;
    H[8]  = r ? c : cc;    H[9]  = r ? zz : gg;   H[10] = (f2){e2, 0.f}; H[11] = c;
    H[12] = r ? gg : zz;   H[13] = r ? c : cc;    H[14] = cc;          H[15] = (f2){e3, 0.f};

    f2 A[16], AN[16];
#pragma unroll
    for (int k = 0; k < 16; ++k) {
        A[k]  = (f2){DTF * H[k].y, -DTF * H[k].x}; // -i*dt*H
        AN[k] = ib(A[k]);
    }

    // X = I + A/6
#pragma unroll
    for (int k = 0; k < 16; ++k) X[k] = A[k] * (1.f / 6.f);
    X[0].x += 1.f; X[5].x += 1.f; X[10].x += 1.f; X[15].x += 1.f;

    // Horner: X = (A*X)/kk + I, pair-cooperative (own rows 0,1 then merge)
#pragma unroll
    for (int kk = 5; kk >= 1; --kk) {
        f2 Zh[8];
        float rk = 1.0f / (float)kk;
#pragma unroll
        for (int i = 0; i < 2; ++i)
#pragma unroll
            for (int b = 0; b < 4; ++b) {
                f2 acc = (f2){0.f, 0.f};
#pragma unroll
                for (int k = 0; k < 4; ++k)
                    acc = cmac_p(acc, X[4 * k + b], A[4 * i + k], AN[4 * i + k]);
                Zh[4 * i + b] = acc * rk;
            }
        Zh[0].x += 1.f; Zh[5].x += 1.f; // diag of own rows; partner covers 2,3
        pair_merge(Zh, X);
    }
}

// ---------- kA: expm + in-block scan; S (canonical chunk planes) + totals T ----------
__global__ __launch_bounds__(512, 2) void kA_scan(
    const float* __restrict__ ux, const float* __restrict__ uy,
    const float* __restrict__ v1p, const float* __restrict__ v2p,
    const float* __restrict__ Jp, float4* __restrict__ S4,
    float4* __restrict__ T4) {
    __shared__ float4 WT[7][8];
    int b = blockIdx.x, t = threadIdx.x;
    int lane = t & 63, w = t >> 6, r = lane & 1, s = lane >> 1;
    int r5 = 5 * r;
    int n = b * 256 + w * 32 + s;

    f2 X[16];
    expmU_pair(ux[n], uy[n], *v1p, *v2p, *Jp, r, X);
    wave_scan_pair(X, s);
    block_combine_pair(X, WT, w, s, r5); // X = U_n ... U_{256b} (own basis)

    // store own half (rows 0,1 own = canonical chunks q^r5), SoA planes
#pragma unroll
    for (int q = 0; q < 4; ++q)
        S4[(size_t)(q ^ r5) * NSAMP + n] =
            make_float4(X[2 * q].x, X[2 * q].y, X[2 * q + 1].x, X[2 * q + 1].y);
    if (w == 7 && s == 31) {
#pragma unroll
        for (int q = 0; q < 4; ++q)
            T4[b * 8 + (q ^ r5)] =
                make_float4(X[2 * q].x, X[2 * q].y, X[2 * q + 1].x, X[2 * q + 1].y);
    }
}

// ---------- kB: redundant totals-scan -> prefix cols; load S; apply; out ----------
__global__ __launch_bounds__(512, 2) void kB_apply(
    const float4* __restrict__ S4, const float4* __restrict__ T4,
    float* __restrict__ out) {
    __shared__ float4 WT[7][8];
    __shared__ f2 WB[8];
    int b = blockIdx.x, t = threadIdx.x;
    int lane = t & 63, w = t >> 6, r = lane & 1, s = lane >> 1;
    int r5 = 5 * r, m = w * 32 + s;

    // scan the 256 block totals (pair-split, 8 waves x 32)
    f2 X[16];
#pragma unroll
    for (int c = 0; c < 8; ++c) {
        float4 v = T4[m * 8 + (c ^ r5)];
        X[2 * c]     = (f2){v.x, v.y};
        X[2 * c + 1] = (f2){v.z, v.w};
    }
    wave_scan_pair(X, s);
    block_combine_pair(X, WT, w, s, r5); // X = T_m ... T_0

    // publish exclusive prefix (canonical cols 0,3) for this block
    if (b == 0) {
        if (t == 0) {
#pragma unroll
            for (int i = 0; i < 8; ++i) WB[i] = (f2){0.f, 0.f};
            WB[0] = (f2){1.f, 0.f};
            WB[7] = (f2){1.f, 0.f};
        }
    } else if (m == b - 1) {
        if (r == 0) { WB[0] = X[0]; WB[1] = X[4]; WB[4] = X[3]; WB[5] = X[7]; }
        else        { WB[2] = X[2]; WB[3] = X[6]; WB[6] = X[1]; WB[7] = X[5]; }
    }
    __syncthreads();

    // load own half of in-block matrix, apply prefix cols, measure
    int n = b * 256 + m;
    f2 M[8], MN[8];
#pragma unroll
    for (int q = 0; q < 4; ++q) {
        float4 v = S4[(size_t)(q ^ r5) * NSAMP + n];
        M[2 * q]     = (f2){v.x, v.y};
        M[2 * q + 1] = (f2){v.z, v.w};
    }
#pragma unroll
    for (int j = 0; j < 8; ++j) MN[j] = ib(M[j]);

    int twor = 2 * r;
    f2 w0[4], w3[4];
#pragma unroll
    for (int a = 0; a < 4; ++a) {
        w0[a] = WB[a ^ twor];       // col0 in own row order
        w3[a] = WB[4 + (a ^ twor)]; // col3 in own row order
    }
    f2 v4[4]; // v4[0..1] = (M*w0) own rows; v4[2..3] = (M*w3) own rows
#pragma unroll
    for (int i = 0; i < 2; ++i) {
        f2 a0 = (f2){0.f, 0.f}, a3 = (f2){0.f, 0.f};
#pragma unroll
        for (int k = 0; k < 4; ++k) {
            a0 = cmac_p(a0, w0[k], M[4 * i + k], MN[4 * i + k]);
            a3 = cmac_p(a3, w3[k], M[4 * i + k], MN[4 * i + k]);
        }
        v4[i] = a0; v4[2 + i] = a3;
    }
    // full vectors: partner's own rows are our rows 2,3 (r=0 order = canonical)
    f2 f0[4], f3[4];
    f0[0] = v4[0]; f0[1] = v4[1]; f3[0] = v4[2]; f3[1] = v4[3];
#pragma unroll
    for (int i = 0; i < 2; ++i) {
        f2 p0, p3;
        p0.x = __shfl_xor(v4[i].x, 1, 64);     p0.y = __shfl_xor(v4[i].y, 1, 64);
        p3.x = __shfl_xor(v4[2 + i].x, 1, 64); p3.y = __shfl_xor(v4[2 + i].y, 1, 64);
        f0[2 + i] = p0; f3[2 + i] = p3;
    }
    float re0 = rec(f0[0], f0[1]) + rec(f0[0], f0[2]) +
                rec(f0[1], f0[3]) + rec(f0[2], f0[3]);
    float re3 = rec(f3[0], f3[1]) + rec(f3[0], f3[2]) +
                rec(f3[1], f3[3]) + rec(f3[2], f3[3]);
    if (r == 0) out[n] = 0.25f * (re0 - re3);
}

extern "C" void kernel_launch(void* const* d_in, const int* in_sizes, int n_in,
                              void* d_out, int out_size, void* d_ws, size_t ws_size,
                              hipStream_t stream) {
    const float* ux = (const float*)d_in[0];
    const float* uy = (const float*)d_in[1];
    const float* v1 = (const float*)d_in[2];
    const float* v2 = (const float*)d_in[3];
    const float* J  = (const float*)d_in[4];
    float* out = (float*)d_out;

    char* ws = (char*)d_ws;
    // layout: S4 (8 chunk-planes * 65536 float4 = 8 MiB) | T4 (32 KiB)
    float4* S4 = (float4*)(ws);
    float4* T4 = (float4*)(ws + (size_t)8 * NSAMP * 16);

    kA_scan<<<256, 512, 0, stream>>>(ux, uy, v1, v2, J, S4, T4);
    kB_apply<<<256, 512, 0, stream>>>(S4, T4, out);
}